// Round 8
// baseline (111.669 us; speedup 1.0000x reference)
//
#include <hip/hip_runtime.h>
#include <math.h>

// Problem constants (fixed by the reference): x,y are [4, 64, 64, 64] fp32.
constexpr int B_   = 4;
constexpr int C_   = 64;
constexpr int HW   = 4096;         // N = 64*64
constexpr int ROWS = B_ * HW;      // 16384

constexpr float SIGMA    = 0.1f;
constexpr float EPS_MIN  = 1e-5f;
constexpr float EPS_NORM = 1e-12f;
constexpr float LOG2E    = 1.44269504088896340736f;

// Fused-kernel geometry: block owns XR=16 x-rows x ALL 4096 y-cols of one
// batch (dmin block-local -> no global dmin/S, one atomicAdd per block).
// 4 waves split y into quarters; each wave stages its y through PRIVATE
// LDS (no __syncthreads in the sweeps, only same-wave lgkmcnt ordering).
// XR=16 -> 1024 blocks (4/CU), SRW=32 -> 32 KB LDS/block: 4 waves/SIMD.
constexpr int XR  = 16;            // x-rows per block (1 MFMA col-tile)
constexpr int YQ  = HW / 4;        // 1024 y-rows per wave
constexpr int SRW = 32;            // y-rows per wave-private stage (4 KB)
constexpr int NSW = YQ / SRW;      // 32 stages per sweep

using short8  = __attribute__((ext_vector_type(8))) short;   // 8 bf16
using floatx4 = __attribute__((ext_vector_type(4))) float;

__device__ inline ushort f2bf(float f) {           // RNE float->bf16
    unsigned u = __float_as_uint(f);
    unsigned r = u + 0x7FFFu + ((u >> 16) & 1u);
    return (ushort)(r >> 16);
}

// ---------------------------------------------------------------------------
// Normalize along C, write bf16 [B][N][C] point-major; zero the total accum.
__global__ __launch_bounds__(256) void nrm_kernel(const float* __restrict__ x,
                                                  const float* __restrict__ y,
                                                  ushort* __restrict__ xn,
                                                  ushort* __restrict__ yn,
                                                  float* __restrict__ total) {
    int p = blockIdx.x * 256 + threadIdx.x;        // 0 .. 2*ROWS-1
    if (p == 0) *total = 0.0f;
    const float* src; ushort* dst; int q;
    if (p < ROWS) { src = x; dst = xn; q = p; }
    else          { src = y; dst = yn; q = p - ROWS; }
    int b = q >> 12;
    int n = q & (HW - 1);
    const float* base = src + ((size_t)b * C_) * HW + n;  // coalesced over n
    float v[C_];
    float ss = 0.0f;
#pragma unroll
    for (int c = 0; c < C_; ++c) {
        v[c] = base[(size_t)c * HW];
        ss = fmaf(v[c], v[c], ss);
    }
    float scale = 1.0f / fmaxf(sqrtf(ss), EPS_NORM);
    short8* o = (short8*)(dst + (size_t)q * C_);
#pragma unroll
    for (int c8 = 0; c8 < C_ / 8; ++c8) {
        short8 pk;
#pragma unroll
        for (int j = 0; j < 8; ++j) pk[j] = (short)f2bf(v[c8 * 8 + j] * scale);
        o[c8] = pk;
    }
}

// ---------------------------------------------------------------------------
// Fused kernel. Swapped-operand MFMA (A=y, B=x): D col = x point (lane&15),
// D row = y point -> per-x-row reduction over y is an in-register
// accumulate; cross-kgrp combine is 2 shfls per sweep.
// Sweep 1: max dot -> dmin (block-local LDS reduce).
// Sweep 2: S_row = sum_m exp2((dmin-d)*kk2), kk2 = log2e/(sigma*(dmin+eps));
//          then one atomicAdd per block of sum_rows(1/S + eps).
__global__ __launch_bounds__(256, 4) void main_kernel(const ushort* __restrict__ xn,
                                                      const ushort* __restrict__ yn,
                                                      float* __restrict__ total) {
    __shared__ short8 stg[4][2][SRW * 8];          // wave-private dbuf, 32 KB
    __shared__ float  red[4][XR];
    __shared__ float  dmf[XR];

    const int tid  = threadIdx.x;
    const int wid  = tid >> 6;
    const int lane = tid & 63;
    const int lrow = lane & 15;                    // x-col within tile
    const int kgrp = lane >> 4;                    // k-group 0..3

    const int blk   = blockIdx.x;
    const int b     = blk >> 8;                    // 256 blocks per batch
    const int nbase = (blk & 255) * XR;

    // x B-fragment (16 x-rows), pinned in registers.
    const ushort* xb = xn + (size_t)(b * HW + nbase) * C_;
    short8 xf0 = *(const short8*)(xb + lrow * C_ + kgrp * 8);        // k 0..31
    short8 xf1 = *(const short8*)(xb + lrow * C_ + 32 + kgrp * 8);   // k 32..63

    // This wave's y-quarter, in 16B units (8 units per y-row).
    const short8* yq = (const short8*)(yn + (size_t)(b * HW + wid * YQ) * C_);
    // Staging: lane handles units g*64+lane (g=0..3) per stage. Swizzled
    // write slot: row = g*8+(lane>>3), slot = lane&7; (row&7) == lane>>3.
    const int wbase = (lane >> 3) * 8 + ((lane & 7) ^ (lane >> 3));

    short8 v[4];
    float st0 = -INFINITY;                         // sweep-1 max dot

    // ---------------- sweep 1: max dot ----------------
#pragma unroll
    for (int g = 0; g < 4; ++g) v[g] = yq[g * 64 + lane];
#pragma unroll
    for (int g = 0; g < 4; ++g) stg[wid][0][g * 64 + wbase] = v[g];

    for (int s = 0; s < NSW; ++s) {
        int cur = s & 1;
        if (s + 1 < NSW) {                         // issue-early (T14)
#pragma unroll
            for (int g = 0; g < 4; ++g) v[g] = yq[(s + 1) * 256 + g * 64 + lane];
        }
#pragma unroll
        for (int yt = 0; yt < 2; ++yt) {
            int p = yt * 16 + lrow, q = p & 7;
            short8 ya0 = stg[wid][cur][p * 8 + (kgrp ^ q)];         // k 0..31
            short8 ya1 = stg[wid][cur][p * 8 + ((kgrp + 4) ^ q)];   // k 32..63
            floatx4 acc = {0.0f, 0.0f, 0.0f, 0.0f};
            acc = __builtin_amdgcn_mfma_f32_16x16x32_bf16(ya0, xf0, acc, 0, 0, 0);
            acc = __builtin_amdgcn_mfma_f32_16x16x32_bf16(ya1, xf1, acc, 0, 0, 0);
            st0 = fmaxf(st0,
                  fmaxf(fmaxf(acc[0], acc[1]), fmaxf(acc[2], acc[3])));
        }
        if (s + 1 < NSW) {                         // write-late (T14)
#pragma unroll
            for (int g = 0; g < 4; ++g) stg[wid][cur ^ 1][g * 64 + wbase] = v[g];
        }
    }

    // Combine the 4 k-groups, then the 4 waves (disjoint y-subsets).
#pragma unroll
    for (int off = 16; off < 64; off <<= 1)
        st0 = fmaxf(st0, __shfl_xor(st0, off));
    if (kgrp == 0) red[wid][lrow] = st0;
    __syncthreads();
    if (tid < XR) {
        float m = fmaxf(fmaxf(red[0][tid], red[1][tid]),
                        fmaxf(red[2][tid], red[3][tid]));
        dmf[tid] = sqrtf(fmaxf(fmaf(-2.0f, m, 2.0f), 0.0f));   // dmin
    }
    __syncthreads();

    float dm  = dmf[lrow];
    float kk2 = LOG2E / (SIGMA * (dm + EPS_MIN));
    float c02 = dm * kk2;

    // ---------------- sweep 2: exp-sum ----------------
    float s2 = 0.0f;
#pragma unroll
    for (int g = 0; g < 4; ++g) v[g] = yq[g * 64 + lane];
#pragma unroll
    for (int g = 0; g < 4; ++g) stg[wid][0][g * 64 + wbase] = v[g];

    for (int s = 0; s < NSW; ++s) {
        int cur = s & 1;
        if (s + 1 < NSW) {
#pragma unroll
            for (int g = 0; g < 4; ++g) v[g] = yq[(s + 1) * 256 + g * 64 + lane];
        }
#pragma unroll
        for (int yt = 0; yt < 2; ++yt) {
            int p = yt * 16 + lrow, q = p & 7;
            short8 ya0 = stg[wid][cur][p * 8 + (kgrp ^ q)];
            short8 ya1 = stg[wid][cur][p * 8 + ((kgrp + 4) ^ q)];
            floatx4 acc = {0.0f, 0.0f, 0.0f, 0.0f};
            acc = __builtin_amdgcn_mfma_f32_16x16x32_bf16(ya0, xf0, acc, 0, 0, 0);
            acc = __builtin_amdgcn_mfma_f32_16x16x32_bf16(ya1, xf1, acc, 0, 0, 0);
#pragma unroll
            for (int r = 0; r < 4; ++r) {
                float d2 = fmaxf(fmaf(-2.0f, acc[r], 2.0f), 0.0f);
                float d  = __builtin_amdgcn_sqrtf(d2);
                s2 += __builtin_amdgcn_exp2f(fmaf(-kk2, d, c02));
            }
        }
        if (s + 1 < NSW) {
#pragma unroll
            for (int g = 0; g < 4; ++g) stg[wid][cur ^ 1][g * 64 + wbase] = v[g];
        }
    }

#pragma unroll
    for (int off = 16; off < 64; off <<= 1)
        s2 += __shfl_xor(s2, off);
    if (kgrp == 0) red[wid][lrow] = s2;
    __syncthreads();

    // Block partial of sum(1/S + eps) -> one atomicAdd.
    if (tid < 64) {
        float acc = 0.0f;
        if (tid < XR) {
            float Ssum = red[0][tid] + red[1][tid] + red[2][tid] + red[3][tid];
            acc = __builtin_amdgcn_rcpf(Ssum) + EPS_MIN;
        }
#pragma unroll
        for (int off = 8; off > 0; off >>= 1) acc += __shfl_down(acc, off);
        if (tid == 0) atomicAdd(total, acc);
    }
}

// ---------------------------------------------------------------------------
__global__ void final_kernel(const float* __restrict__ total,
                             float* __restrict__ out) {
    out[0] = -logf(total[0] / (float)ROWS);
}

// ---------------------------------------------------------------------------
extern "C" void kernel_launch(void* const* d_in, const int* in_sizes, int n_in,
                              void* d_out, int out_size, void* d_ws, size_t ws_size,
                              hipStream_t stream) {
    const float* x = (const float*)d_in[0];
    const float* y = (const float*)d_in[1];
    float* out = (float*)d_out;

    char* ws = (char*)d_ws;
    size_t nrm_bytes = (size_t)ROWS * C_ * sizeof(ushort);   // 2 MB each
    ushort* xn    = (ushort*)(ws);
    ushort* yn    = (ushort*)(ws + nrm_bytes);
    float*  total = (float*)(ws + 2 * nrm_bytes);

    hipLaunchKernelGGL(nrm_kernel, dim3(2 * ROWS / 256), dim3(256), 0, stream,
                       x, y, xn, yn, total);
    hipLaunchKernelGGL(main_kernel, dim3(ROWS / XR), dim3(256), 0, stream,
                       xn, yn, total);
    hipLaunchKernelGGL(final_kernel, dim3(1), dim3(1), 0, stream, total, out);
}

// Round 9
// 99.032 us; speedup vs baseline: 1.1276x; 1.1276x over previous
//
#include <hip/hip_runtime.h>
#include <math.h>

// Problem constants (fixed by the reference): x,y are [4, 64, 64, 64] fp32.
constexpr int B_   = 4;
constexpr int C_   = 64;
constexpr int HW   = 4096;         // N = 64*64
constexpr int ROWS = B_ * HW;      // 16384

constexpr float SIGMA    = 0.1f;
constexpr float EPS_MIN  = 1e-5f;
constexpr float EPS_NORM = 1e-12f;
constexpr float LOG2E    = 1.44269504088896340736f;

// Fused-kernel geometry: block owns XR=32 x-rows x ALL 4096 y-cols of one
// batch (dmin block-local -> no global dmin/S, one atomicAdd per block).
// 8 waves (512 threads) split y 8-ways; each wave stages its y through
// PRIVATE LDS (no __syncthreads in sweeps, same-wave lgkmcnt ordering only).
// R6 economics kept (xt=2 -> 0.5 LDS reads/MFMA, 256 blocks... XR=32 ->
// 512 blocks, 256MB y L2 traffic/sweep); occupancy doubled vs R6 via
// 8 waves/block: 2 blocks/CU x 8 = 4 waves/SIMD.
constexpr int XR  = 32;            // x-rows per block (2 MFMA col-tiles)
constexpr int YW  = HW / 8;        // 512 y-rows per wave
constexpr int SRW = 32;            // y-rows per wave-private stage (4 KB)
constexpr int NSW = YW / SRW;      // 16 stages per sweep

using short8  = __attribute__((ext_vector_type(8))) short;   // 8 bf16
using floatx4 = __attribute__((ext_vector_type(4))) float;

__device__ inline ushort f2bf(float f) {           // RNE float->bf16
    unsigned u = __float_as_uint(f);
    unsigned r = u + 0x7FFFu + ((u >> 16) & 1u);
    return (ushort)(r >> 16);
}

// ---------------------------------------------------------------------------
// Normalize along C, write bf16 [B][N][C] point-major; zero the total accum.
__global__ __launch_bounds__(256) void nrm_kernel(const float* __restrict__ x,
                                                  const float* __restrict__ y,
                                                  ushort* __restrict__ xn,
                                                  ushort* __restrict__ yn,
                                                  float* __restrict__ total) {
    int p = blockIdx.x * 256 + threadIdx.x;        // 0 .. 2*ROWS-1
    if (p == 0) *total = 0.0f;
    const float* src; ushort* dst; int q;
    if (p < ROWS) { src = x; dst = xn; q = p; }
    else          { src = y; dst = yn; q = p - ROWS; }
    int b = q >> 12;
    int n = q & (HW - 1);
    const float* base = src + ((size_t)b * C_) * HW + n;  // coalesced over n
    float v[C_];
    float ss = 0.0f;
#pragma unroll
    for (int c = 0; c < C_; ++c) {
        v[c] = base[(size_t)c * HW];
        ss = fmaf(v[c], v[c], ss);
    }
    float scale = 1.0f / fmaxf(sqrtf(ss), EPS_NORM);
    short8* o = (short8*)(dst + (size_t)q * C_);
#pragma unroll
    for (int c8 = 0; c8 < C_ / 8; ++c8) {
        short8 pk;
#pragma unroll
        for (int j = 0; j < 8; ++j) pk[j] = (short)f2bf(v[c8 * 8 + j] * scale);
        o[c8] = pk;
    }
}

// ---------------------------------------------------------------------------
// Fused kernel. Swapped-operand MFMA (A=y, B=x): D col = x point (lane&15),
// D row = y point -> per-x-row reduction over y is an in-register
// accumulate; cross-kgrp combine is 2 shfls per sweep.
// Sweep 1: max dot -> dmin (block-local LDS reduce across 8 waves).
// Sweep 2: S_row = sum_m exp2((dmin-d)*kk2), kk2 = log2e/(sigma*(dmin+eps));
//          then one atomicAdd per block of sum_rows(1/S + eps).
__global__ __launch_bounds__(512, 4) void main_kernel(const ushort* __restrict__ xn,
                                                      const ushort* __restrict__ yn,
                                                      float* __restrict__ total) {
    __shared__ short8 stg[8][2][SRW * 8];          // wave-private dbuf, 64 KB
    __shared__ float  red[8][XR];
    __shared__ float  dmf[XR];

    const int tid  = threadIdx.x;
    const int wid  = tid >> 6;                     // 0..7
    const int lane = tid & 63;
    const int lrow = lane & 15;                    // x-col within tile
    const int kgrp = lane >> 4;                    // k-group 0..3

    const int blk   = blockIdx.x;
    const int b     = blk >> 7;                    // 128 blocks per batch
    const int nbase = (blk & 127) * XR;

    // x B-fragments: 2 tiles x (k 0..31, k 32..63), pinned in registers.
    const ushort* xb = xn + (size_t)(b * HW + nbase) * C_;
    short8 xf0[2], xf1[2];
#pragma unroll
    for (int xt = 0; xt < 2; ++xt) {
        xf0[xt] = *(const short8*)(xb + (xt * 16 + lrow) * C_ + kgrp * 8);
        xf1[xt] = *(const short8*)(xb + (xt * 16 + lrow) * C_ + 32 + kgrp * 8);
    }

    // This wave's y-eighth, in 16B units (8 units per y-row).
    const short8* yq = (const short8*)(yn + (size_t)(b * HW + wid * YW) * C_);
    // Staging: lane handles units g*64+lane (g=0..3) per stage. Swizzled
    // write slot: row = g*8+(lane>>3), slot = lane&7; (row&7) == lane>>3.
    const int wbase = (lane >> 3) * 8 + ((lane & 7) ^ (lane >> 3));

    short8 v[4];
    float st0[2] = {-INFINITY, -INFINITY};         // sweep-1 max dot

    // ---------------- sweep 1: max dot ----------------
#pragma unroll
    for (int g = 0; g < 4; ++g) v[g] = yq[g * 64 + lane];
#pragma unroll
    for (int g = 0; g < 4; ++g) stg[wid][0][g * 64 + wbase] = v[g];

    for (int s = 0; s < NSW; ++s) {
        int cur = s & 1;
        if (s + 1 < NSW) {                         // issue-early (T14)
#pragma unroll
            for (int g = 0; g < 4; ++g) v[g] = yq[(s + 1) * 256 + g * 64 + lane];
        }
#pragma unroll
        for (int yt = 0; yt < 2; ++yt) {
            int p = yt * 16 + lrow, q = p & 7;
            short8 ya0 = stg[wid][cur][p * 8 + (kgrp ^ q)];         // k 0..31
            short8 ya1 = stg[wid][cur][p * 8 + ((kgrp + 4) ^ q)];   // k 32..63
#pragma unroll
            for (int xt = 0; xt < 2; ++xt) {
                floatx4 acc = {0.0f, 0.0f, 0.0f, 0.0f};
                acc = __builtin_amdgcn_mfma_f32_16x16x32_bf16(ya0, xf0[xt], acc, 0, 0, 0);
                acc = __builtin_amdgcn_mfma_f32_16x16x32_bf16(ya1, xf1[xt], acc, 0, 0, 0);
                st0[xt] = fmaxf(st0[xt],
                          fmaxf(fmaxf(acc[0], acc[1]), fmaxf(acc[2], acc[3])));
            }
        }
        if (s + 1 < NSW) {                         // write-late (T14)
#pragma unroll
            for (int g = 0; g < 4; ++g) stg[wid][cur ^ 1][g * 64 + wbase] = v[g];
        }
    }

    // Combine the 4 k-groups, then the 8 waves (disjoint y-subsets).
#pragma unroll
    for (int off = 16; off < 64; off <<= 1) {
        st0[0] = fmaxf(st0[0], __shfl_xor(st0[0], off));
        st0[1] = fmaxf(st0[1], __shfl_xor(st0[1], off));
    }
    if (kgrp == 0) { red[wid][lrow] = st0[0]; red[wid][16 + lrow] = st0[1]; }
    __syncthreads();
    if (tid < XR) {
        float m = red[0][tid];
#pragma unroll
        for (int w = 1; w < 8; ++w) m = fmaxf(m, red[w][tid]);
        dmf[tid] = sqrtf(fmaxf(fmaf(-2.0f, m, 2.0f), 0.0f));   // dmin
    }
    __syncthreads();

    float kk2[2], c02[2];
#pragma unroll
    for (int xt = 0; xt < 2; ++xt) {
        float dm = dmf[xt * 16 + lrow];
        kk2[xt] = LOG2E / (SIGMA * (dm + EPS_MIN));
        c02[xt] = dm * kk2[xt];
    }

    // ---------------- sweep 2: exp-sum ----------------
    float s2[2] = {0.0f, 0.0f};
#pragma unroll
    for (int g = 0; g < 4; ++g) v[g] = yq[g * 64 + lane];
#pragma unroll
    for (int g = 0; g < 4; ++g) stg[wid][0][g * 64 + wbase] = v[g];

    for (int s = 0; s < NSW; ++s) {
        int cur = s & 1;
        if (s + 1 < NSW) {
#pragma unroll
            for (int g = 0; g < 4; ++g) v[g] = yq[(s + 1) * 256 + g * 64 + lane];
        }
#pragma unroll
        for (int yt = 0; yt < 2; ++yt) {
            int p = yt * 16 + lrow, q = p & 7;
            short8 ya0 = stg[wid][cur][p * 8 + (kgrp ^ q)];
            short8 ya1 = stg[wid][cur][p * 8 + ((kgrp + 4) ^ q)];
#pragma unroll
            for (int xt = 0; xt < 2; ++xt) {
                floatx4 acc = {0.0f, 0.0f, 0.0f, 0.0f};
                acc = __builtin_amdgcn_mfma_f32_16x16x32_bf16(ya0, xf0[xt], acc, 0, 0, 0);
                acc = __builtin_amdgcn_mfma_f32_16x16x32_bf16(ya1, xf1[xt], acc, 0, 0, 0);
#pragma unroll
                for (int r = 0; r < 4; ++r) {
                    float d2 = fmaxf(fmaf(-2.0f, acc[r], 2.0f), 0.0f);
                    float d  = __builtin_amdgcn_sqrtf(d2);
                    s2[xt] += __builtin_amdgcn_exp2f(fmaf(-kk2[xt], d, c02[xt]));
                }
            }
        }
        if (s + 1 < NSW) {
#pragma unroll
            for (int g = 0; g < 4; ++g) stg[wid][cur ^ 1][g * 64 + wbase] = v[g];
        }
    }

#pragma unroll
    for (int off = 16; off < 64; off <<= 1) {
        s2[0] += __shfl_xor(s2[0], off);
        s2[1] += __shfl_xor(s2[1], off);
    }
    if (kgrp == 0) { red[wid][lrow] = s2[0]; red[wid][16 + lrow] = s2[1]; }
    __syncthreads();

    // Block partial of sum(1/S + eps) -> one atomicAdd.
    if (tid < 64) {
        float acc = 0.0f;
        if (tid < XR) {
            float Ssum = red[0][tid];
#pragma unroll
            for (int w = 1; w < 8; ++w) Ssum += red[w][tid];
            acc = __builtin_amdgcn_rcpf(Ssum) + EPS_MIN;
        }
#pragma unroll
        for (int off = 16; off > 0; off >>= 1) acc += __shfl_down(acc, off);
        if (tid == 0) atomicAdd(total, acc);
    }
}

// ---------------------------------------------------------------------------
__global__ void final_kernel(const float* __restrict__ total,
                             float* __restrict__ out) {
    out[0] = -logf(total[0] / (float)ROWS);
}

// ---------------------------------------------------------------------------
extern "C" void kernel_launch(void* const* d_in, const int* in_sizes, int n_in,
                              void* d_out, int out_size, void* d_ws, size_t ws_size,
                              hipStream_t stream) {
    const float* x = (const float*)d_in[0];
    const float* y = (const float*)d_in[1];
    float* out = (float*)d_out;

    char* ws = (char*)d_ws;
    size_t nrm_bytes = (size_t)ROWS * C_ * sizeof(ushort);   // 2 MB each
    ushort* xn    = (ushort*)(ws);
    ushort* yn    = (ushort*)(ws + nrm_bytes);
    float*  total = (float*)(ws + 2 * nrm_bytes);

    hipLaunchKernelGGL(nrm_kernel, dim3(2 * ROWS / 256), dim3(256), 0, stream,
                       x, y, xn, yn, total);
    hipLaunchKernelGGL(main_kernel, dim3(ROWS / XR), dim3(512), 0, stream,
                       xn, yn, total);
    hipLaunchKernelGGL(final_kernel, dim3(1), dim3(1), 0, stream, total, out);
}